// Round 2
// baseline (1133.051 us; speedup 1.0000x reference)
//
#include <hip/hip_runtime.h>

typedef unsigned short u16;
typedef __attribute__((ext_vector_type(4))) unsigned short us4;
typedef __attribute__((ext_vector_type(4))) float f4;
typedef __attribute__((ext_vector_type(8))) short bf16x8;
typedef __attribute__((ext_vector_type(4))) float f32x4;

__device__ __forceinline__ u16 f2bf(float x) {
  unsigned u = __float_as_uint(x);
  return (u16)((u + 0x7FFFu + ((u >> 16) & 1u)) >> 16);
}
__device__ __forceinline__ float b2f(u16 s) {
  return __uint_as_float(((unsigned)s) << 16);
}
__device__ __forceinline__ float sigm(float x) { return 1.f / (1.f + __expf(-x)); }
__device__ __forceinline__ float tanhf_(float x) { return 2.f / (1.f + __expf(-2.f * x)) - 1.f; }

// ---------------------------------------------------------------------------
// Setup kernel 1: convert W_i..W_f, U_i..U_f (fp32 [1024][1024]) to bf16,
// packed gate-major: Wb[g][row][k], Ub[g][row][k].
// ---------------------------------------------------------------------------
__global__ void convert_wu_kernel(const float* __restrict__ w0, const float* __restrict__ w1,
                                  const float* __restrict__ w2, const float* __restrict__ w3,
                                  const float* __restrict__ u0, const float* __restrict__ u1,
                                  const float* __restrict__ u2, const float* __restrict__ u3,
                                  u16* __restrict__ Wb, u16* __restrict__ Ub) {
  int mat = blockIdx.x >> 10;
  int off4 = (int)(blockIdx.x & 1023) * 256 + threadIdx.x;
  const float* src; u16* dst;
  switch (mat) {
    case 0: src = w0; dst = Wb; break;
    case 1: src = w1; dst = Wb + 1048576; break;
    case 2: src = w2; dst = Wb + 2097152; break;
    case 3: src = w3; dst = Wb + 3145728; break;
    case 4: src = u0; dst = Ub; break;
    case 5: src = u1; dst = Ub + 1048576; break;
    case 6: src = u2; dst = Ub + 2097152; break;
    default: src = u3; dst = Ub + 3145728; break;
  }
  f4 v = ((const f4*)src)[off4];
  us4 o = {f2bf(v[0]), f2bf(v[1]), f2bf(v[2]), f2bf(v[3])};
  ((us4*)dst)[off4] = o;
}

// ---------------------------------------------------------------------------
// Setup kernel 2: Xleaf[n][k] = bf16(tokens[leaf_ids[n]][k]).
// ---------------------------------------------------------------------------
__global__ void gather_leaf_kernel(const float* __restrict__ tokens,
                                   const int* __restrict__ ids, u16* __restrict__ Xl) {
  int n = blockIdx.x, t = threadIdx.x;
  int tok = ids[n];
  f4 v = ((const f4*)(tokens + (size_t)tok * 1024))[t];
  us4 o = {f2bf(v[0]), f2bf(v[1]), f2bf(v[2]), f2bf(v[3])};
  ((us4*)(Xl + (size_t)n * 1024))[t] = o;
}

// ---------------------------------------------------------------------------
// Setup kernel 3 (fp32 dots, tiny): xw[op][g][j], leafC[5][j].
// ---------------------------------------------------------------------------
__global__ void precompute_kernel(const float* __restrict__ op_emb,
    const float* __restrict__ w0, const float* __restrict__ w1,
    const float* __restrict__ w2, const float* __restrict__ w3,
    const float* __restrict__ u0, const float* __restrict__ u1,
    const float* __restrict__ u2, const float* __restrict__ u3,
    const float* __restrict__ b0, const float* __restrict__ b1,
    const float* __restrict__ b2, const float* __restrict__ b3,
    const float* __restrict__ h_init,
    float* __restrict__ xw, float* __restrict__ leafC) {
  int id = blockIdx.x * 256 + threadIdx.x;
  if (id < 16384) {
    int op = id >> 12, g = (id >> 10) & 3, j = id & 1023;
    const float* wsrc; const float* bs;
    switch (g) {
      case 0: wsrc = w0; bs = b0; break;
      case 1: wsrc = w1; bs = b1; break;
      case 2: wsrc = w2; bs = b2; break;
      default: wsrc = w3; bs = b3; break;
    }
    const f4* xr = (const f4*)(op_emb + (size_t)op * 1024);
    const f4* wr = (const f4*)(wsrc + (size_t)j * 1024);
    float s = bs[j];
    for (int k = 0; k < 256; ++k) {
      f4 a = xr[k], b = wr[k];
      s += a[0] * b[0] + a[1] * b[1] + a[2] * b[2] + a[3] * b[3];
    }
    xw[id] = s;
  } else if (id < 21504) {
    int id2 = id - 16384;
    int sel = id2 >> 10, j = id2 & 1023;
    const f4* h0 = (const f4*)h_init;
    const f4* h1 = (const f4*)(h_init + 1024);
    float s;
    if (sel < 3) {
      const float* usrc; const float* bs;
      switch (sel) {
        case 0: usrc = u0; bs = b0; break;
        case 1: usrc = u1; bs = b1; break;
        default: usrc = u2; bs = b2; break;
      }
      const f4* wr = (const f4*)(usrc + (size_t)j * 1024);
      s = bs[j];
      for (int k = 0; k < 256; ++k) {
        f4 a0 = h0[k], a1 = h1[k], b = wr[k];
        s += (a0[0] + a1[0]) * b[0] + (a0[1] + a1[1]) * b[1] +
             (a0[2] + a1[2]) * b[2] + (a0[3] + a1[3]) * b[3];
      }
    } else {
      const f4* hs = (sel == 3) ? h0 : h1;
      const f4* wr = (const f4*)(u3 + (size_t)j * 1024);
      s = b3[j];
      for (int k = 0; k < 256; ++k) {
        f4 a = hs[k], b = wr[k];
        s += a[0] * b[0] + a[1] * b[1] + a[2] * b[2] + a[3] * b[3];
      }
    }
    leafC[id2] = s;
  }
}

// ---------------------------------------------------------------------------
// Main fused GEMM + TreeLSTM node kernel — NO-LDS K-loop.
// Block: 256 thr = 4 waves. Tile: 64 A-rows x 64 cols x 4 gates (wave = gate).
// All MFMA fragments are loaded DIRECTLY global->VGPR (each fragment is a
// contiguous 16B segment in row-major bf16):
//   A frag (t, step s): lane reads A[r0+t*16+(lane&15)][s*32 + (lane>>4)*8 ..+8]
//   B frag (f, step s): lane reads Wm[wave*1024+j0+f*16+(lane&15)][same k]
// No __syncthreads in the K-loop -> compiler pipelines with fine vmcnt.
// Explicit depth-1 register double buffer (BK=32 per step, 32 steps).
// Epilogue: gate tiles exchanged via LDS (bf16, stride 66), activations fused.
// ---------------------------------------------------------------------------
__global__ __launch_bounds__(256) void tree_gemm(
    const u16* __restrict__ A, const u16* __restrict__ Wm,
    const float* __restrict__ consts,   // leafC[5][1024] or xw[4][4][1024]
    const int* __restrict__ ops,        // nullptr for leaf
    const float* __restrict__ c_in,     // c_init[2][1024] or child c
    float* __restrict__ c_out, u16* __restrict__ h_out,
    int nrows, int m_parents, int is_leaf, float* __restrict__ out_root) {
  __shared__ __align__(16) u16 smem[4 * 64 * 66];  // 33792 B, epilogue only

  const int tid = threadIdx.x;
  const int wave = tid >> 6;
  const int lane = tid & 63;
  const int r0 = blockIdx.x * 64;
  const int j0 = blockIdx.y * 64;
  const int ln15 = lane & 15, quad = lane >> 4;

  // per-lane fragment base pointers (k-offset advances 32 elems = 64 B / step;
  // 32 steps * 64 B = 2 KB max -> fits 13-bit signed immediate offsets)
  const u16* pA[4];
  const u16* pB[4];
#pragma unroll
  for (int t = 0; t < 4; ++t) {
    int row = r0 + t * 16 + ln15;
    if (row >= nrows) row = nrows - 1;
    pA[t] = A + (size_t)row * 1024 + quad * 8;
    pB[t] = Wm + (size_t)(wave * 1024 + j0 + t * 16 + ln15) * 1024 + quad * 8;
  }

  f32x4 acc[4][4];
#pragma unroll
  for (int t = 0; t < 4; ++t)
#pragma unroll
    for (int f = 0; f < 4; ++f) acc[t][f] = (f32x4){0.f, 0.f, 0.f, 0.f};

  bf16x8 afr[2][4], bfr[2][4];
#pragma unroll
  for (int t = 0; t < 4; ++t) {
    afr[0][t] = *(const bf16x8*)(pA[t]);
    bfr[0][t] = *(const bf16x8*)(pB[t]);
  }

#pragma unroll 4
  for (int s = 0; s < 32; ++s) {
    const int cur = s & 1, nxt = cur ^ 1;
    if (s < 31) {
      const int ko = (s + 1) * 32;
#pragma unroll
      for (int t = 0; t < 4; ++t) {
        afr[nxt][t] = *(const bf16x8*)(pA[t] + ko);
        bfr[nxt][t] = *(const bf16x8*)(pB[t] + ko);
      }
    }
#pragma unroll
    for (int t = 0; t < 4; ++t)
#pragma unroll
      for (int f = 0; f < 4; ++f)
        acc[t][f] = __builtin_amdgcn_mfma_f32_16x16x32_bf16(afr[cur][t], bfr[cur][f],
                                                            acc[t][f], 0, 0, 0);
  }

  // ---- epilogue: exchange gate tiles through LDS (bf16, stride 66) ----
  // C/D layout: row = quad*4 + k (within 16-row frag t), col = ln15 (in frag f)
#pragma unroll
  for (int t = 0; t < 4; ++t)
#pragma unroll
    for (int f = 0; f < 4; ++f)
#pragma unroll
      for (int k = 0; k < 4; ++k) {
        int row = t * 16 + quad * 4 + k;
        int col = f * 16 + ln15;
        smem[(wave * 64 + row) * 66 + col] = f2bf(acc[t][f][k]);
      }
  __syncthreads();

  if (is_leaf) {
    for (int e = tid; e < 4096; e += 256) {
      int r = e >> 6, j = e & 63;
      int col = j0 + j, n = r0 + r;
      float p0 = b2f(smem[(0 * 64 + r) * 66 + j]);
      float p1 = b2f(smem[(1 * 64 + r) * 66 + j]);
      float p2 = b2f(smem[(2 * 64 + r) * 66 + j]);
      float p3 = b2f(smem[(3 * 64 + r) * 66 + j]);
      float i_ = sigm(p0 + consts[col]);
      float o_ = sigm(p1 + consts[1024 + col]);
      float u_ = tanhf_(p2 + consts[2048 + col]);
      float f0 = sigm(p3 + consts[3072 + col]);
      float f1 = sigm(p3 + consts[4096 + col]);
      float c = i_ * u_ + f0 * c_in[col] + f1 * c_in[1024 + col];
      float h = o_ * tanhf_(c);
      c_out[(size_t)n * 1024 + col] = c;
      h_out[(size_t)n * 1024 + col] = f2bf(h);
    }
  } else {
    for (int e = tid; e < 2048; e += 256) {
      int p = e >> 6, j = e & 63;
      int np = (r0 >> 1) + p;
      if (np >= m_parents) break;
      int col = j0 + j;
      int op = ops[np];
      const float* xwop = consts + ((unsigned)(op * 4) << 10);
      float p0a = b2f(smem[(0 * 64 + 2 * p) * 66 + j]), p0b = b2f(smem[(0 * 64 + 2 * p + 1) * 66 + j]);
      float p1a = b2f(smem[(1 * 64 + 2 * p) * 66 + j]), p1b = b2f(smem[(1 * 64 + 2 * p + 1) * 66 + j]);
      float p2a = b2f(smem[(2 * 64 + 2 * p) * 66 + j]), p2b = b2f(smem[(2 * 64 + 2 * p + 1) * 66 + j]);
      float p3a = b2f(smem[(3 * 64 + 2 * p) * 66 + j]), p3b = b2f(smem[(3 * 64 + 2 * p + 1) * 66 + j]);
      float i_ = sigm(p0a + p0b + xwop[col]);
      float o_ = sigm(p1a + p1b + xwop[1024 + col]);
      float u_ = tanhf_(p2a + p2b + xwop[2048 + col]);
      float f0 = sigm(p3a + xwop[3072 + col]);
      float f1 = sigm(p3b + xwop[3072 + col]);
      float c = i_ * u_ + f0 * c_in[(size_t)(r0 + 2 * p) * 1024 + col]
                        + f1 * c_in[(size_t)(r0 + 2 * p + 1) * 1024 + col];
      float h = o_ * tanhf_(c);
      if (m_parents == 1) {
        out_root[col] = c;
        out_root[1024 + col] = h;
      } else {
        c_out[(size_t)np * 1024 + col] = c;
        h_out[(size_t)np * 1024 + col] = f2bf(h);
      }
    }
  }
}

// ---------------------------------------------------------------------------
extern "C" void kernel_launch(void* const* d_in, const int* in_sizes, int n_in,
                              void* d_out, int out_size, void* d_ws, size_t ws_size,
                              hipStream_t stream) {
  const float* tokens = (const float*)d_in[0];
  const int* leaf_ids = (const int*)d_in[1];
  const int* op_ids = (const int*)d_in[2];
  const float* W0 = (const float*)d_in[3];
  const float* W1 = (const float*)d_in[4];
  const float* W2 = (const float*)d_in[5];
  const float* W3 = (const float*)d_in[6];
  const float* U0 = (const float*)d_in[7];
  const float* U1 = (const float*)d_in[8];
  const float* U2 = (const float*)d_in[9];
  const float* U3 = (const float*)d_in[10];
  const float* B0 = (const float*)d_in[11];
  const float* B1 = (const float*)d_in[12];
  const float* B2 = (const float*)d_in[13];
  const float* B3 = (const float*)d_in[14];
  const float* op_emb = (const float*)d_in[15];
  const float* c_init = (const float*)d_in[16];
  const float* h_init = (const float*)d_in[17];
  float* out = (float*)d_out;

  char* ws = (char*)d_ws;
  u16* Wb = (u16*)ws;
  u16* Ub = Wb + (size_t)4 * 1024 * 1024;
  u16* Xl = Ub + (size_t)4 * 1024 * 1024;
  u16* hA = Xl + (size_t)8192 * 1024;
  u16* hB = hA + (size_t)8192 * 1024;
  float* cA = (float*)(hB + (size_t)4096 * 1024);
  float* cB = cA + (size_t)8192 * 1024;
  float* xw = cB + (size_t)4096 * 1024;
  float* lc = xw + 16 * 1024;

  convert_wu_kernel<<<8192, 256, 0, stream>>>(W0, W1, W2, W3, U0, U1, U2, U3, Wb, Ub);
  gather_leaf_kernel<<<8192, 256, 0, stream>>>(tokens, leaf_ids, Xl);
  precompute_kernel<<<84, 256, 0, stream>>>(op_emb, W0, W1, W2, W3, U0, U1, U2, U3,
                                            B0, B1, B2, B3, h_init, xw, lc);

  tree_gemm<<<dim3(128, 16), 256, 0, stream>>>(Xl, Wb, lc, nullptr, c_init,
                                               cA, hA, 8192, 0, 1, out);

  const u16* hin = hA; const float* cin = cA;
  u16* hout = hB; float* cout = cB;
  for (int l = 12; l >= 0; --l) {
    int m = 1 << l;
    int rb = (2 * m) / 64; if (rb < 1) rb = 1;
    tree_gemm<<<dim3(rb, 16), 256, 0, stream>>>(hin, Ub, xw, op_ids + (m - 1), cin,
                                                cout, hout, 2 * m, m, 0, out);
    const u16* th = hin; hin = hout; hout = (u16*)th;
    const float* tc = cin; cin = cout; cout = (float*)tc;
  }
}

// Round 3
// 818.685 us; speedup vs baseline: 1.3840x; 1.3840x over previous
//
#include <hip/hip_runtime.h>

typedef unsigned short u16;
typedef __attribute__((ext_vector_type(4))) unsigned short us4;
typedef __attribute__((ext_vector_type(4))) float f4;
typedef __attribute__((ext_vector_type(8))) short bf16x8;
typedef __attribute__((ext_vector_type(4))) float f32x4;

__device__ __forceinline__ u16 f2bf(float x) {
  unsigned u = __float_as_uint(x);
  return (u16)((u + 0x7FFFu + ((u >> 16) & 1u)) >> 16);
}
__device__ __forceinline__ float b2f(u16 s) {
  return __uint_as_float(((unsigned)s) << 16);
}
__device__ __forceinline__ float sigm(float x) { return 1.f / (1.f + __expf(-x)); }
__device__ __forceinline__ float tanhf_(float x) { return 2.f / (1.f + __expf(-2.f * x)) - 1.f; }

// ---------------------------------------------------------------------------
// Setup kernel 1: convert W_i..W_f, U_i..U_f (fp32 [1024][1024]) to bf16,
// packed gate-major: Wb[g][row][k], Ub[g][row][k].
// ---------------------------------------------------------------------------
__global__ void convert_wu_kernel(const float* __restrict__ w0, const float* __restrict__ w1,
                                  const float* __restrict__ w2, const float* __restrict__ w3,
                                  const float* __restrict__ u0, const float* __restrict__ u1,
                                  const float* __restrict__ u2, const float* __restrict__ u3,
                                  u16* __restrict__ Wb, u16* __restrict__ Ub) {
  int mat = blockIdx.x >> 10;
  int off4 = (int)(blockIdx.x & 1023) * 256 + threadIdx.x;
  const float* src; u16* dst;
  switch (mat) {
    case 0: src = w0; dst = Wb; break;
    case 1: src = w1; dst = Wb + 1048576; break;
    case 2: src = w2; dst = Wb + 2097152; break;
    case 3: src = w3; dst = Wb + 3145728; break;
    case 4: src = u0; dst = Ub; break;
    case 5: src = u1; dst = Ub + 1048576; break;
    case 6: src = u2; dst = Ub + 2097152; break;
    default: src = u3; dst = Ub + 3145728; break;
  }
  f4 v = ((const f4*)src)[off4];
  us4 o = {f2bf(v[0]), f2bf(v[1]), f2bf(v[2]), f2bf(v[3])};
  ((us4*)dst)[off4] = o;
}

// ---------------------------------------------------------------------------
// Setup kernel 2: Xleaf[n][k] = bf16(tokens[leaf_ids[n]][k]).
// ---------------------------------------------------------------------------
__global__ void gather_leaf_kernel(const float* __restrict__ tokens,
                                   const int* __restrict__ ids, u16* __restrict__ Xl) {
  int n = blockIdx.x, t = threadIdx.x;
  int tok = ids[n];
  f4 v = ((const f4*)(tokens + (size_t)tok * 1024))[t];
  us4 o = {f2bf(v[0]), f2bf(v[1]), f2bf(v[2]), f2bf(v[3])};
  ((us4*)(Xl + (size_t)n * 1024))[t] = o;
}

// ---------------------------------------------------------------------------
// Setup kernel 3 (fp32 dots, tiny): xw[op][g][j], leafC[5][j].
// ---------------------------------------------------------------------------
__global__ void precompute_kernel(const float* __restrict__ op_emb,
    const float* __restrict__ w0, const float* __restrict__ w1,
    const float* __restrict__ w2, const float* __restrict__ w3,
    const float* __restrict__ u0, const float* __restrict__ u1,
    const float* __restrict__ u2, const float* __restrict__ u3,
    const float* __restrict__ b0, const float* __restrict__ b1,
    const float* __restrict__ b2, const float* __restrict__ b3,
    const float* __restrict__ h_init,
    float* __restrict__ xw, float* __restrict__ leafC) {
  int id = blockIdx.x * 256 + threadIdx.x;
  if (id < 16384) {
    int op = id >> 12, g = (id >> 10) & 3, j = id & 1023;
    const float* wsrc; const float* bs;
    switch (g) {
      case 0: wsrc = w0; bs = b0; break;
      case 1: wsrc = w1; bs = b1; break;
      case 2: wsrc = w2; bs = b2; break;
      default: wsrc = w3; bs = b3; break;
    }
    const f4* xr = (const f4*)(op_emb + (size_t)op * 1024);
    const f4* wr = (const f4*)(wsrc + (size_t)j * 1024);
    float s = bs[j];
    for (int k = 0; k < 256; ++k) {
      f4 a = xr[k], b = wr[k];
      s += a[0] * b[0] + a[1] * b[1] + a[2] * b[2] + a[3] * b[3];
    }
    xw[id] = s;
  } else if (id < 21504) {
    int id2 = id - 16384;
    int sel = id2 >> 10, j = id2 & 1023;
    const f4* h0 = (const f4*)h_init;
    const f4* h1 = (const f4*)(h_init + 1024);
    float s;
    if (sel < 3) {
      const float* usrc; const float* bs;
      switch (sel) {
        case 0: usrc = u0; bs = b0; break;
        case 1: usrc = u1; bs = b1; break;
        default: usrc = u2; bs = b2; break;
      }
      const f4* wr = (const f4*)(usrc + (size_t)j * 1024);
      s = bs[j];
      for (int k = 0; k < 256; ++k) {
        f4 a0 = h0[k], a1 = h1[k], b = wr[k];
        s += (a0[0] + a1[0]) * b[0] + (a0[1] + a1[1]) * b[1] +
             (a0[2] + a1[2]) * b[2] + (a0[3] + a1[3]) * b[3];
      }
    } else {
      const f4* hs = (sel == 3) ? h0 : h1;
      const f4* wr = (const f4*)(u3 + (size_t)j * 1024);
      s = b3[j];
      for (int k = 0; k < 256; ++k) {
        f4 a = hs[k], b = wr[k];
        s += a[0] * b[0] + a[1] * b[1] + a[2] * b[2] + a[3] * b[3];
      }
    }
    leafC[id2] = s;
  }
}

// ---------------------------------------------------------------------------
// Main fused GEMM + TreeLSTM node kernel — HYBRID:
//   A (activations, 4x intra-block reuse) staged via double-buffered LDS,
//     global_load_lds width=16, XOR-granule swizzle, ONE barrier per chunk
//     (stage for ch+1 issued right after the barrier -> cheap drain).
//   B (weights, zero intra-block reuse)  loaded DIRECTLY global->VGPR,
//     L2-resident via XCD-pinned striping: 1D grid, stripe = blockIdx&15,
//     so (assuming round-robin block->XCD) XCD k only touches stripes
//     {k, k+8} = 1 MB of weights -> fits 4 MB per-XCD L2.
// Block: 256 thr = 4 waves. Tile: 64 A-rows x 64 cols x 4 gates (wave=gate).
// Epilogue: gate tiles exchanged via LDS bf16 stride 68 (conflict-free).
// ---------------------------------------------------------------------------
__global__ __launch_bounds__(256, 3) void tree_gemm(
    const u16* __restrict__ A, const u16* __restrict__ Wm,
    const float* __restrict__ consts,   // leafC[5][1024] or xw[4][4][1024]
    const int* __restrict__ ops,        // nullptr for leaf
    const float* __restrict__ c_in,     // c_init[2][1024] or child c
    float* __restrict__ c_out, u16* __restrict__ h_out,
    int nrows, int m_parents, int is_leaf, float* __restrict__ out_root) {
  // 34816 B. K-loop uses first 16 KB as A double buffer; epilogue uses all.
  __shared__ __align__(16) u16 smem[4 * 64 * 68];
  char* smem_c = (char*)smem;

  const int tid = threadIdx.x;
  const int wave = tid >> 6;
  const int lane = tid & 63;
  const int stripe = blockIdx.x & 15;
  const int rowblk = blockIdx.x >> 4;
  const int r0 = rowblk * 64;
  const int j0 = stripe * 64;
  const int ln15 = lane & 15, quad = lane >> 4;
  const int sub = lane >> 3, gsel = lane & 7;

  // ---- A staging addresses (2 global_load_lds x 16 B per wave per chunk) ---
  // LDS layout per buffer: row slot r at bytes [r*128, r*128+128), granule g
  // (16B) stored at position g ^ (r&7). Lane l writes slot (grp*8 + l/8),
  // position l%8  -> must fetch source granule (l%8) ^ (l/8).
  const char* pAsrc[2];
  unsigned a_dst[2];
#pragma unroll
  for (int i = 0; i < 2; ++i) {
    int slot = (wave * 2 + i) * 8 + sub;
    int row = r0 + slot; if (row >= nrows) row = nrows - 1;
    pAsrc[i] = (const char*)(A + (size_t)row * 1024 + (unsigned)((gsel ^ sub) * 8));
    a_dst[i] = (unsigned)((wave * 2 + i) * 1024 + lane * 16);
  }
  // ---- B direct-load pointers (16 B contiguous per lane per fragment) -----
  const char* pB[4];
#pragma unroll
  for (int f = 0; f < 4; ++f)
    pB[f] = (const char*)(Wm + (size_t)(wave * 1024 + j0 + f * 16 + ln15) * 1024 + quad * 8);

  // ---- A fragment LDS read addresses (per buffer-relative) ----------------
  unsigned a_rd[4][2];
#pragma unroll
  for (int t = 0; t < 4; ++t) {
    int slot = t * 16 + ln15;
#pragma unroll
    for (int ks = 0; ks < 2; ++ks) {
      int g = (ks * 4 + quad) ^ (slot & 7);
      a_rd[t][ks] = (unsigned)(slot * 128 + g * 16);
    }
  }

  f32x4 acc[4][4];
#pragma unroll
  for (int t = 0; t < 4; ++t)
#pragma unroll
    for (int f = 0; f < 4; ++f) acc[t][f] = (f32x4){0.f, 0.f, 0.f, 0.f};

  // prologue: stage chunk 0 into buffer 0
#pragma unroll
  for (int i = 0; i < 2; ++i)
    __builtin_amdgcn_global_load_lds(
        (const __attribute__((address_space(1))) void*)(pAsrc[i]),
        (__attribute__((address_space(3))) void*)(smem_c + a_dst[i]), 16, 0, 0);

  for (int ch = 0; ch < 16; ++ch) {
    __syncthreads();  // drains stage(ch) (issued a full chunk of MFMAs ago)
    if (ch < 15) {
      const unsigned chb = (unsigned)(ch + 1) * 128;
      const unsigned bb = (unsigned)(((ch + 1) & 1) * 8192);
#pragma unroll
      for (int i = 0; i < 2; ++i)
        __builtin_amdgcn_global_load_lds(
            (const __attribute__((address_space(1))) void*)(pAsrc[i] + chb),
            (__attribute__((address_space(3))) void*)(smem_c + bb + a_dst[i]), 16, 0, 0);
    }
    const unsigned cb = (unsigned)((ch & 1) * 8192);
    const unsigned kb = (unsigned)ch * 128;
#pragma unroll
    for (int ks = 0; ks < 2; ++ks) {
      bf16x8 bfr[4], af[4];
#pragma unroll
      for (int f = 0; f < 4; ++f)
        bfr[f] = *(const bf16x8*)(pB[f] + kb + ks * 64);
#pragma unroll
      for (int t = 0; t < 4; ++t)
        af[t] = *(const bf16x8*)(smem_c + cb + a_rd[t][ks]);
#pragma unroll
      for (int t = 0; t < 4; ++t)
#pragma unroll
        for (int f = 0; f < 4; ++f)
          acc[t][f] = __builtin_amdgcn_mfma_f32_16x16x32_bf16(af[t], bfr[f],
                                                              acc[t][f], 0, 0, 0);
    }
  }

  // ---- epilogue: exchange gate tiles through LDS (bf16, stride 68) --------
  __syncthreads();  // all waves done reading A buffers before overwrite
#pragma unroll
  for (int t = 0; t < 4; ++t)
#pragma unroll
    for (int f = 0; f < 4; ++f)
#pragma unroll
      for (int k = 0; k < 4; ++k) {
        int row = t * 16 + quad * 4 + k;
        int col = f * 16 + ln15;
        smem[(wave * 64 + row) * 68 + col] = f2bf(acc[t][f][k]);
      }
  __syncthreads();

  if (is_leaf) {
    for (int e = tid; e < 4096; e += 256) {
      int r = e >> 6, j = e & 63;
      int col = j0 + j, n = r0 + r;
      float p0 = b2f(smem[(0 * 64 + r) * 68 + j]);
      float p1 = b2f(smem[(1 * 64 + r) * 68 + j]);
      float p2 = b2f(smem[(2 * 64 + r) * 68 + j]);
      float p3 = b2f(smem[(3 * 64 + r) * 68 + j]);
      float i_ = sigm(p0 + consts[col]);
      float o_ = sigm(p1 + consts[1024 + col]);
      float u_ = tanhf_(p2 + consts[2048 + col]);
      float f0 = sigm(p3 + consts[3072 + col]);
      float f1 = sigm(p3 + consts[4096 + col]);
      float c = i_ * u_ + f0 * c_in[col] + f1 * c_in[1024 + col];
      float h = o_ * tanhf_(c);
      c_out[(size_t)n * 1024 + col] = c;
      h_out[(size_t)n * 1024 + col] = f2bf(h);
    }
  } else {
    for (int e = tid; e < 2048; e += 256) {
      int p = e >> 6, j = e & 63;
      int np = (r0 >> 1) + p;
      if (np >= m_parents) break;
      int col = j0 + j;
      int op = ops[np];
      const float* xwop = consts + ((unsigned)(op * 4) << 10);
      float p0a = b2f(smem[(0 * 64 + 2 * p) * 68 + j]), p0b = b2f(smem[(0 * 64 + 2 * p + 1) * 68 + j]);
      float p1a = b2f(smem[(1 * 64 + 2 * p) * 68 + j]), p1b = b2f(smem[(1 * 64 + 2 * p + 1) * 68 + j]);
      float p2a = b2f(smem[(2 * 64 + 2 * p) * 68 + j]), p2b = b2f(smem[(2 * 64 + 2 * p + 1) * 68 + j]);
      float p3a = b2f(smem[(3 * 64 + 2 * p) * 68 + j]), p3b = b2f(smem[(3 * 64 + 2 * p + 1) * 68 + j]);
      float i_ = sigm(p0a + p0b + xwop[col]);
      float o_ = sigm(p1a + p1b + xwop[1024 + col]);
      float u_ = tanhf_(p2a + p2b + xwop[2048 + col]);
      float f0 = sigm(p3a + xwop[3072 + col]);
      float f1 = sigm(p3b + xwop[3072 + col]);
      float c = i_ * u_ + f0 * c_in[(size_t)(r0 + 2 * p) * 1024 + col]
                        + f1 * c_in[(size_t)(r0 + 2 * p + 1) * 1024 + col];
      float h = o_ * tanhf_(c);
      if (m_parents == 1) {
        out_root[col] = c;
        out_root[1024 + col] = h;
      } else {
        c_out[(size_t)np * 1024 + col] = c;
        h_out[(size_t)np * 1024 + col] = f2bf(h);
      }
    }
  }
}

// ---------------------------------------------------------------------------
extern "C" void kernel_launch(void* const* d_in, const int* in_sizes, int n_in,
                              void* d_out, int out_size, void* d_ws, size_t ws_size,
                              hipStream_t stream) {
  const float* tokens = (const float*)d_in[0];
  const int* leaf_ids = (const int*)d_in[1];
  const int* op_ids = (const int*)d_in[2];
  const float* W0 = (const float*)d_in[3];
  const float* W1 = (const float*)d_in[4];
  const float* W2 = (const float*)d_in[5];
  const float* W3 = (const float*)d_in[6];
  const float* U0 = (const float*)d_in[7];
  const float* U1 = (const float*)d_in[8];
  const float* U2 = (const float*)d_in[9];
  const float* U3 = (const float*)d_in[10];
  const float* B0 = (const float*)d_in[11];
  const float* B1 = (const float*)d_in[12];
  const float* B2 = (const float*)d_in[13];
  const float* B3 = (const float*)d_in[14];
  const float* op_emb = (const float*)d_in[15];
  const float* c_init = (const float*)d_in[16];
  const float* h_init = (const float*)d_in[17];
  float* out = (float*)d_out;

  char* ws = (char*)d_ws;
  u16* Wb = (u16*)ws;
  u16* Ub = Wb + (size_t)4 * 1024 * 1024;
  u16* Xl = Ub + (size_t)4 * 1024 * 1024;
  u16* hA = Xl + (size_t)8192 * 1024;
  u16* hB = hA + (size_t)8192 * 1024;
  float* cA = (float*)(hB + (size_t)4096 * 1024);
  float* cB = cA + (size_t)8192 * 1024;
  float* xw = cB + (size_t)4096 * 1024;
  float* lc = xw + 16 * 1024;

  convert_wu_kernel<<<8192, 256, 0, stream>>>(W0, W1, W2, W3, U0, U1, U2, U3, Wb, Ub);
  gather_leaf_kernel<<<8192, 256, 0, stream>>>(tokens, leaf_ids, Xl);
  precompute_kernel<<<84, 256, 0, stream>>>(op_emb, W0, W1, W2, W3, U0, U1, U2, U3,
                                            B0, B1, B2, B3, h_init, xw, lc);

  // leaves: 8192 rows, 1D grid = rowblocks*16 (stripe = low 4 bits)
  tree_gemm<<<128 * 16, 256, 0, stream>>>(Xl, Wb, lc, nullptr, c_init,
                                          cA, hA, 8192, 0, 1, out);

  const u16* hin = hA; const float* cin = cA;
  u16* hout = hB; float* cout = cB;
  for (int l = 12; l >= 0; --l) {
    int m = 1 << l;
    int rb = (2 * m) / 64; if (rb < 1) rb = 1;
    tree_gemm<<<rb * 16, 256, 0, stream>>>(hin, Ub, xw, op_ids + (m - 1), cin,
                                           cout, hout, 2 * m, m, 0, out);
    const u16* th = hin; hin = hout; hout = (u16*)th;
    const float* tc = cin; cin = cout; cout = (float*)tc;
  }
}

// Round 4
// 741.404 us; speedup vs baseline: 1.5283x; 1.1042x over previous
//
#include <hip/hip_runtime.h>

typedef unsigned short u16;
typedef __attribute__((ext_vector_type(4))) unsigned short us4;
typedef __attribute__((ext_vector_type(4))) float f4;
typedef __attribute__((ext_vector_type(8))) short bf16x8;
typedef __attribute__((ext_vector_type(4))) float f32x4;

__device__ __forceinline__ u16 f2bf(float x) {
  unsigned u = __float_as_uint(x);
  return (u16)((u + 0x7FFFu + ((u >> 16) & 1u)) >> 16);
}
__device__ __forceinline__ float b2f(u16 s) {
  return __uint_as_float(((unsigned)s) << 16);
}
__device__ __forceinline__ float sigm(float x) { return 1.f / (1.f + __expf(-x)); }
__device__ __forceinline__ float tanhf_(float x) { return 2.f / (1.f + __expf(-2.f * x)) - 1.f; }

// ---------------------------------------------------------------------------
// Setup kernel 1: convert W/U fp32 -> bf16, gate-major.
// ---------------------------------------------------------------------------
__global__ void convert_wu_kernel(const float* __restrict__ w0, const float* __restrict__ w1,
                                  const float* __restrict__ w2, const float* __restrict__ w3,
                                  const float* __restrict__ u0, const float* __restrict__ u1,
                                  const float* __restrict__ u2, const float* __restrict__ u3,
                                  u16* __restrict__ Wb, u16* __restrict__ Ub) {
  int mat = blockIdx.x >> 10;
  int off4 = (int)(blockIdx.x & 1023) * 256 + threadIdx.x;
  const float* src; u16* dst;
  switch (mat) {
    case 0: src = w0; dst = Wb; break;
    case 1: src = w1; dst = Wb + 1048576; break;
    case 2: src = w2; dst = Wb + 2097152; break;
    case 3: src = w3; dst = Wb + 3145728; break;
    case 4: src = u0; dst = Ub; break;
    case 5: src = u1; dst = Ub + 1048576; break;
    case 6: src = u2; dst = Ub + 2097152; break;
    default: src = u3; dst = Ub + 3145728; break;
  }
  f4 v = ((const f4*)src)[off4];
  us4 o = {f2bf(v[0]), f2bf(v[1]), f2bf(v[2]), f2bf(v[3])};
  ((us4*)dst)[off4] = o;
}

// ---------------------------------------------------------------------------
// Setup kernel 2: Xleaf[n][k] = bf16(tokens[leaf_ids[n]][k]).
// ---------------------------------------------------------------------------
__global__ void gather_leaf_kernel(const float* __restrict__ tokens,
                                   const int* __restrict__ ids, u16* __restrict__ Xl) {
  int n = blockIdx.x, t = threadIdx.x;
  int tok = ids[n];
  f4 v = ((const f4*)(tokens + (size_t)tok * 1024))[t];
  us4 o = {f2bf(v[0]), f2bf(v[1]), f2bf(v[2]), f2bf(v[3])};
  ((us4*)(Xl + (size_t)n * 1024))[t] = o;
}

// ---------------------------------------------------------------------------
// Setup kernel 3 (fp32 dots, tiny): xw[op][g][j], leafC[5][j].
// ---------------------------------------------------------------------------
__global__ void precompute_kernel(const float* __restrict__ op_emb,
    const float* __restrict__ w0, const float* __restrict__ w1,
    const float* __restrict__ w2, const float* __restrict__ w3,
    const float* __restrict__ u0, const float* __restrict__ u1,
    const float* __restrict__ u2, const float* __restrict__ u3,
    const float* __restrict__ b0, const float* __restrict__ b1,
    const float* __restrict__ b2, const float* __restrict__ b3,
    const float* __restrict__ h_init,
    float* __restrict__ xw, float* __restrict__ leafC) {
  int id = blockIdx.x * 256 + threadIdx.x;
  if (id < 16384) {
    int op = id >> 12, g = (id >> 10) & 3, j = id & 1023;
    const float* wsrc; const float* bs;
    switch (g) {
      case 0: wsrc = w0; bs = b0; break;
      case 1: wsrc = w1; bs = b1; break;
      case 2: wsrc = w2; bs = b2; break;
      default: wsrc = w3; bs = b3; break;
    }
    const f4* xr = (const f4*)(op_emb + (size_t)op * 1024);
    const f4* wr = (const f4*)(wsrc + (size_t)j * 1024);
    float s = bs[j];
    for (int k = 0; k < 256; ++k) {
      f4 a = xr[k], b = wr[k];
      s += a[0] * b[0] + a[1] * b[1] + a[2] * b[2] + a[3] * b[3];
    }
    xw[id] = s;
  } else if (id < 21504) {
    int id2 = id - 16384;
    int sel = id2 >> 10, j = id2 & 1023;
    const f4* h0 = (const f4*)h_init;
    const f4* h1 = (const f4*)(h_init + 1024);
    float s;
    if (sel < 3) {
      const float* usrc; const float* bs;
      switch (sel) {
        case 0: usrc = u0; bs = b0; break;
        case 1: usrc = u1; bs = b1; break;
        default: usrc = u2; bs = b2; break;
      }
      const f4* wr = (const f4*)(usrc + (size_t)j * 1024);
      s = bs[j];
      for (int k = 0; k < 256; ++k) {
        f4 a0 = h0[k], a1 = h1[k], b = wr[k];
        s += (a0[0] + a1[0]) * b[0] + (a0[1] + a1[1]) * b[1] +
             (a0[2] + a1[2]) * b[2] + (a0[3] + a1[3]) * b[3];
      }
    } else {
      const f4* hs = (sel == 3) ? h0 : h1;
      const f4* wr = (const f4*)(u3 + (size_t)j * 1024);
      s = b3[j];
      for (int k = 0; k < 256; ++k) {
        f4 a = hs[k], b = wr[k];
        s += a[0] * b[0] + a[1] * b[1] + a[2] * b[2] + a[3] * b[3];
      }
    }
    leafC[id2] = s;
  }
}

// ---------------------------------------------------------------------------
// Main fused GEMM + TreeLSTM node kernel.
// Template NRT = row-fragments per wave (8 -> 128-row tile, 4 -> 64-row).
// Block: 256 thr = 4 waves, wave = gate. Tile: NRT*16 rows x 64 cols x 4 gates.
// A: double-buffered LDS (global_load_lds w=16, XOR-granule swizzle, ONE
//    barrier per chunk - stage for ch+1 issued right after the barrier).
// B: direct global->VGPR; each B fragment feeds NRT MFMAs (register reuse).
//    Stripe-pinned 1D grid (stripe = blockIdx & 15) for L2 locality.
// Epilogue: gate exchange via LDS bf16 stride 68 (verified conflict-free),
//    processed in NRT/4 passes of 64 rows.
// ---------------------------------------------------------------------------
template <int NRT>
__global__ __launch_bounds__(256, (NRT == 8 ? 2 : 3)) void tree_gemm(
    const u16* __restrict__ A, const u16* __restrict__ Wm,
    const float* __restrict__ consts,   // leafC[5][1024] or xw[4][4][1024]
    const int* __restrict__ ops,        // nullptr for leaf
    const float* __restrict__ c_in,     // c_init[2][1024] or child c
    float* __restrict__ c_out, u16* __restrict__ h_out,
    int nrows, int m_parents, int is_leaf, float* __restrict__ out_root) {
  // 34816 B; K-loop A dbuf uses first NRT*4096 B (<=32768), epilogue all.
  __shared__ __align__(16) u16 smem[4 * 64 * 68];
  char* smem_c = (char*)smem;

  const int tid = threadIdx.x;
  const int wave = tid >> 6;
  const int lane = tid & 63;
  const int stripe = blockIdx.x & 15;
  const int rowblk = blockIdx.x >> 4;
  const int r0 = rowblk * (NRT * 16);
  const int j0 = stripe * 64;
  const int ln15 = lane & 15, quad = lane >> 4;
  const int sub = lane >> 3, gsel = lane & 7;

  // ---- A staging (NRT/2 global_load_lds x 16B per wave per chunk) ---------
  // Buffer layout: row slot r occupies bytes [r*128, r*128+128); 16B granule g
  // stored at position g ^ (r&7).
  const int NST = NRT / 2;
  const char* pAsrc[NST];
  unsigned a_dst[NST];
#pragma unroll
  for (int i = 0; i < NST; ++i) {
    int slot = (wave * NST + i) * 8 + sub;
    int row = r0 + slot; if (row >= nrows) row = nrows - 1;
    pAsrc[i] = (const char*)(A + (size_t)row * 1024 + (unsigned)((gsel ^ sub) * 8));
    a_dst[i] = (unsigned)((wave * NST + i) * 1024 + lane * 16);
  }
  // ---- B direct-load pointers (16B contiguous per lane per fragment) ------
  const char* pB[4];
#pragma unroll
  for (int f = 0; f < 4; ++f)
    pB[f] = (const char*)(Wm + (size_t)(wave * 1024 + j0 + f * 16 + ln15) * 1024 + quad * 8);

  // ---- A fragment LDS read addresses --------------------------------------
  unsigned a_rd[NRT][2];
#pragma unroll
  for (int t = 0; t < NRT; ++t) {
    int slot = t * 16 + ln15;
#pragma unroll
    for (int ks = 0; ks < 2; ++ks) {
      int g = (ks * 4 + quad) ^ (slot & 7);
      a_rd[t][ks] = (unsigned)(slot * 128 + g * 16);
    }
  }

  f32x4 acc[NRT][4];
#pragma unroll
  for (int t = 0; t < NRT; ++t)
#pragma unroll
    for (int f = 0; f < 4; ++f) acc[t][f] = (f32x4){0.f, 0.f, 0.f, 0.f};

  // prologue: stage chunk 0 into buffer 0
#pragma unroll
  for (int i = 0; i < NST; ++i)
    __builtin_amdgcn_global_load_lds(
        (const __attribute__((address_space(1))) void*)(pAsrc[i]),
        (__attribute__((address_space(3))) void*)(smem_c + a_dst[i]), 16, 0, 0);

  for (int ch = 0; ch < 16; ++ch) {
    __syncthreads();  // drains stage(ch) (issued a full chunk of MFMAs ago)
    if (ch < 15) {
      const unsigned chb = (unsigned)(ch + 1) * 128;
      const unsigned bb = (unsigned)(((ch + 1) & 1) * (NRT * 2048));
#pragma unroll
      for (int i = 0; i < NST; ++i)
        __builtin_amdgcn_global_load_lds(
            (const __attribute__((address_space(1))) void*)(pAsrc[i] + chb),
            (__attribute__((address_space(3))) void*)(smem_c + bb + a_dst[i]), 16, 0, 0);
    }
    const unsigned cb = (unsigned)((ch & 1) * (NRT * 2048));
    const unsigned kb = (unsigned)ch * 128;
#pragma unroll
    for (int ks = 0; ks < 2; ++ks) {
      bf16x8 bfr[4], af[NRT];
#pragma unroll
      for (int f = 0; f < 4; ++f)
        bfr[f] = *(const bf16x8*)(pB[f] + kb + ks * 64);
#pragma unroll
      for (int t = 0; t < NRT; ++t)
        af[t] = *(const bf16x8*)(smem_c + cb + a_rd[t][ks]);
#pragma unroll
      for (int t = 0; t < NRT; ++t)
#pragma unroll
        for (int f = 0; f < 4; ++f)
          acc[t][f] = __builtin_amdgcn_mfma_f32_16x16x32_bf16(af[t], bfr[f],
                                                              acc[t][f], 0, 0, 0);
    }
  }

  // ---- epilogue: NRT/4 passes of 64 rows through LDS (stride 68) ----------
#pragma unroll
  for (int half = 0; half < NRT / 4; ++half) {
    __syncthreads();  // pass 0: A-buffer WAR; pass 1: prior reads done
#pragma unroll
    for (int tt = 0; tt < 4; ++tt) {
      int t = half * 4 + tt;
#pragma unroll
      for (int f = 0; f < 4; ++f)
#pragma unroll
        for (int k = 0; k < 4; ++k) {
          int row = tt * 16 + quad * 4 + k;
          int col = f * 16 + ln15;
          smem[(wave * 64 + row) * 68 + col] = f2bf(acc[t][f][k]);
        }
    }
    __syncthreads();
    const int rbase = r0 + half * 64;

    if (is_leaf) {
      for (int e = tid; e < 4096; e += 256) {
        int r = e >> 6, j = e & 63;
        int col = j0 + j, n = rbase + r;
        float p0 = b2f(smem[(0 * 64 + r) * 68 + j]);
        float p1 = b2f(smem[(1 * 64 + r) * 68 + j]);
        float p2 = b2f(smem[(2 * 64 + r) * 68 + j]);
        float p3 = b2f(smem[(3 * 64 + r) * 68 + j]);
        float i_ = sigm(p0 + consts[col]);
        float o_ = sigm(p1 + consts[1024 + col]);
        float u_ = tanhf_(p2 + consts[2048 + col]);
        float f0 = sigm(p3 + consts[3072 + col]);
        float f1 = sigm(p3 + consts[4096 + col]);
        float c = i_ * u_ + f0 * c_in[col] + f1 * c_in[1024 + col];
        float h = o_ * tanhf_(c);
        c_out[(size_t)n * 1024 + col] = c;
        h_out[(size_t)n * 1024 + col] = f2bf(h);
      }
    } else {
      for (int e = tid; e < 2048; e += 256) {
        int p = e >> 6, j = e & 63;
        int np = (rbase >> 1) + p;
        if (np >= m_parents) break;
        int col = j0 + j;
        int op = ops[np];
        const float* xwop = consts + ((unsigned)(op * 4) << 10);
        float p0a = b2f(smem[(0 * 64 + 2 * p) * 68 + j]), p0b = b2f(smem[(0 * 64 + 2 * p + 1) * 68 + j]);
        float p1a = b2f(smem[(1 * 64 + 2 * p) * 68 + j]), p1b = b2f(smem[(1 * 64 + 2 * p + 1) * 68 + j]);
        float p2a = b2f(smem[(2 * 64 + 2 * p) * 68 + j]), p2b = b2f(smem[(2 * 64 + 2 * p + 1) * 68 + j]);
        float p3a = b2f(smem[(3 * 64 + 2 * p) * 68 + j]), p3b = b2f(smem[(3 * 64 + 2 * p + 1) * 68 + j]);
        float i_ = sigm(p0a + p0b + xwop[col]);
        float o_ = sigm(p1a + p1b + xwop[1024 + col]);
        float u_ = tanhf_(p2a + p2b + xwop[2048 + col]);
        float f0 = sigm(p3a + xwop[3072 + col]);
        float f1 = sigm(p3b + xwop[3072 + col]);
        float c = i_ * u_ + f0 * c_in[(size_t)(rbase + 2 * p) * 1024 + col]
                          + f1 * c_in[(size_t)(rbase + 2 * p + 1) * 1024 + col];
        float h = o_ * tanhf_(c);
        if (m_parents == 1) {
          out_root[col] = c;
          out_root[1024 + col] = h;
        } else {
          c_out[(size_t)np * 1024 + col] = c;
          h_out[(size_t)np * 1024 + col] = f2bf(h);
        }
      }
    }
  }
}

// ---------------------------------------------------------------------------
extern "C" void kernel_launch(void* const* d_in, const int* in_sizes, int n_in,
                              void* d_out, int out_size, void* d_ws, size_t ws_size,
                              hipStream_t stream) {
  const float* tokens = (const float*)d_in[0];
  const int* leaf_ids = (const int*)d_in[1];
  const int* op_ids = (const int*)d_in[2];
  const float* W0 = (const float*)d_in[3];
  const float* W1 = (const float*)d_in[4];
  const float* W2 = (const float*)d_in[5];
  const float* W3 = (const float*)d_in[6];
  const float* U0 = (const float*)d_in[7];
  const float* U1 = (const float*)d_in[8];
  const float* U2 = (const float*)d_in[9];
  const float* U3 = (const float*)d_in[10];
  const float* B0 = (const float*)d_in[11];
  const float* B1 = (const float*)d_in[12];
  const float* B2 = (const float*)d_in[13];
  const float* B3 = (const float*)d_in[14];
  const float* op_emb = (const float*)d_in[15];
  const float* c_init = (const float*)d_in[16];
  const float* h_init = (const float*)d_in[17];
  float* out = (float*)d_out;

  char* ws = (char*)d_ws;
  u16* Wb = (u16*)ws;
  u16* Ub = Wb + (size_t)4 * 1024 * 1024;
  u16* Xl = Ub + (size_t)4 * 1024 * 1024;
  u16* hA = Xl + (size_t)8192 * 1024;
  u16* hB = hA + (size_t)8192 * 1024;
  float* cA = (float*)(hB + (size_t)4096 * 1024);
  float* cB = cA + (size_t)8192 * 1024;
  float* xw = cB + (size_t)4096 * 1024;
  float* lc = xw + 16 * 1024;

  convert_wu_kernel<<<8192, 256, 0, stream>>>(W0, W1, W2, W3, U0, U1, U2, U3, Wb, Ub);
  gather_leaf_kernel<<<8192, 256, 0, stream>>>(tokens, leaf_ids, Xl);
  precompute_kernel<<<84, 256, 0, stream>>>(op_emb, W0, W1, W2, W3, U0, U1, U2, U3,
                                            B0, B1, B2, B3, h_init, xw, lc);

  // leaves: 8192 rows -> NRT=8 (128-row blocks), 64 rowgroups x 16 stripes
  tree_gemm<8><<<64 * 16, 256, 0, stream>>>(Xl, Wb, lc, nullptr, c_init,
                                            cA, hA, 8192, 0, 1, out);

  const u16* hin = hA; const float* cin = cA;
  u16* hout = hB; float* cout = cB;
  for (int l = 12; l >= 0; --l) {
    int m = 1 << l;
    int nrows = 2 * m;
    if (nrows >= 4096) {
      int rg = nrows / 128;
      tree_gemm<8><<<rg * 16, 256, 0, stream>>>(hin, Ub, xw, op_ids + (m - 1), cin,
                                                cout, hout, nrows, m, 0, out);
    } else {
      int rg = (nrows + 63) / 64;
      tree_gemm<4><<<rg * 16, 256, 0, stream>>>(hin, Ub, xw, op_ids + (m - 1), cin,
                                                cout, hout, nrows, m, 0, out);
    }
    const u16* th = hin; hin = hout; hout = (u16*)th;
    const float* tc = cin; cin = cout; cout = (float*)tc;
  }
}

// Round 5
// 600.740 us; speedup vs baseline: 1.8861x; 1.2342x over previous
//
#include <hip/hip_runtime.h>

typedef unsigned short u16;
typedef __attribute__((ext_vector_type(4))) unsigned short us4;
typedef __attribute__((ext_vector_type(4))) float f4;
typedef __attribute__((ext_vector_type(8))) short bf16x8;
typedef __attribute__((ext_vector_type(4))) float f32x4;

__device__ __forceinline__ u16 f2bf(float x) {
  unsigned u = __float_as_uint(x);
  return (u16)((u + 0x7FFFu + ((u >> 16) & 1u)) >> 16);
}
__device__ __forceinline__ float b2f(u16 s) {
  return __uint_as_float(((unsigned)s) << 16);
}
__device__ __forceinline__ float sigm(float x) { return 1.f / (1.f + __expf(-x)); }
__device__ __forceinline__ float tanhf_(float x) { return 2.f / (1.f + __expf(-2.f * x)) - 1.f; }

// ---------------------------------------------------------------------------
// Setup kernel 1: convert W/U fp32 -> bf16, gate-major.
// ---------------------------------------------------------------------------
__global__ void convert_wu_kernel(const float* __restrict__ w0, const float* __restrict__ w1,
                                  const float* __restrict__ w2, const float* __restrict__ w3,
                                  const float* __restrict__ u0, const float* __restrict__ u1,
                                  const float* __restrict__ u2, const float* __restrict__ u3,
                                  u16* __restrict__ Wb, u16* __restrict__ Ub) {
  int mat = blockIdx.x >> 10;
  int off4 = (int)(blockIdx.x & 1023) * 256 + threadIdx.x;
  const float* src; u16* dst;
  switch (mat) {
    case 0: src = w0; dst = Wb; break;
    case 1: src = w1; dst = Wb + 1048576; break;
    case 2: src = w2; dst = Wb + 2097152; break;
    case 3: src = w3; dst = Wb + 3145728; break;
    case 4: src = u0; dst = Ub; break;
    case 5: src = u1; dst = Ub + 1048576; break;
    case 6: src = u2; dst = Ub + 2097152; break;
    default: src = u3; dst = Ub + 3145728; break;
  }
  f4 v = ((const f4*)src)[off4];
  us4 o = {f2bf(v[0]), f2bf(v[1]), f2bf(v[2]), f2bf(v[3])};
  ((us4*)dst)[off4] = o;
}

// ---------------------------------------------------------------------------
// Setup kernel 2: Xleaf[n][k] = bf16(tokens[leaf_ids[n]][k]).
// ---------------------------------------------------------------------------
__global__ void gather_leaf_kernel(const float* __restrict__ tokens,
                                   const int* __restrict__ ids, u16* __restrict__ Xl) {
  int n = blockIdx.x, t = threadIdx.x;
  int tok = ids[n];
  f4 v = ((const f4*)(tokens + (size_t)tok * 1024))[t];
  us4 o = {f2bf(v[0]), f2bf(v[1]), f2bf(v[2]), f2bf(v[3])};
  ((us4*)(Xl + (size_t)n * 1024))[t] = o;
}

// ---------------------------------------------------------------------------
// Setup kernel 3 (fp32 dots, tiny): xw[op][g][j], leafC[5][j].
// ---------------------------------------------------------------------------
__global__ void precompute_kernel(const float* __restrict__ op_emb,
    const float* __restrict__ w0, const float* __restrict__ w1,
    const float* __restrict__ w2, const float* __restrict__ w3,
    const float* __restrict__ u0, const float* __restrict__ u1,
    const float* __restrict__ u2, const float* __restrict__ u3,
    const float* __restrict__ b0, const float* __restrict__ b1,
    const float* __restrict__ b2, const float* __restrict__ b3,
    const float* __restrict__ h_init,
    float* __restrict__ xw, float* __restrict__ leafC) {
  int id = blockIdx.x * 256 + threadIdx.x;
  if (id < 16384) {
    int op = id >> 12, g = (id >> 10) & 3, j = id & 1023;
    const float* wsrc; const float* bs;
    switch (g) {
      case 0: wsrc = w0; bs = b0; break;
      case 1: wsrc = w1; bs = b1; break;
      case 2: wsrc = w2; bs = b2; break;
      default: wsrc = w3; bs = b3; break;
    }
    const f4* xr = (const f4*)(op_emb + (size_t)op * 1024);
    const f4* wr = (const f4*)(wsrc + (size_t)j * 1024);
    float s = bs[j];
    for (int k = 0; k < 256; ++k) {
      f4 a = xr[k], b = wr[k];
      s += a[0] * b[0] + a[1] * b[1] + a[2] * b[2] + a[3] * b[3];
    }
    xw[id] = s;
  } else if (id < 21504) {
    int id2 = id - 16384;
    int sel = id2 >> 10, j = id2 & 1023;
    const f4* h0 = (const f4*)h_init;
    const f4* h1 = (const f4*)(h_init + 1024);
    float s;
    if (sel < 3) {
      const float* usrc; const float* bs;
      switch (sel) {
        case 0: usrc = u0; bs = b0; break;
        case 1: usrc = u1; bs = b1; break;
        default: usrc = u2; bs = b2; break;
      }
      const f4* wr = (const f4*)(usrc + (size_t)j * 1024);
      s = bs[j];
      for (int k = 0; k < 256; ++k) {
        f4 a0 = h0[k], a1 = h1[k], b = wr[k];
        s += (a0[0] + a1[0]) * b[0] + (a0[1] + a1[1]) * b[1] +
             (a0[2] + a1[2]) * b[2] + (a0[3] + a1[3]) * b[3];
      }
    } else {
      const f4* hs = (sel == 3) ? h0 : h1;
      const f4* wr = (const f4*)(u3 + (size_t)j * 1024);
      s = b3[j];
      for (int k = 0; k < 256; ++k) {
        f4 a = hs[k], b = wr[k];
        s += a[0] * b[0] + a[1] * b[1] + a[2] * b[2] + a[3] * b[3];
      }
    }
    leafC[id2] = s;
  }
}

// ---------------------------------------------------------------------------
// Main fused GEMM + TreeLSTM node kernel.
// Template <NRT, NCT>: wave tile = NRT*16 rows x NCT*16 cols, 4 waves = 4
// gates. A staged via dbuf LDS (global_load_lds w=16, XOR-granule swizzle).
// B loaded global->VGPR, prefetched ONE FULL CHUNK AHEAD across the barrier
// so ks0 MFMAs never wait on vmem, and the pre-barrier vmcnt(0) drain only
// sees old loads. Stage loads are issued AFTER nothing depends on them
// within the chunk (B for this chunk already in regs -> compiler emits
// vmcnt waits that exclude them).  K-loop fully unrolled (imm offsets).
// Epilogue: gate tiles via LDS stride 68 (bank-verified: quads at bank
// offsets 0/8/16/24 -> conflict-free stores).
// ---------------------------------------------------------------------------
template <int NRT, int NCT>
__global__ __launch_bounds__(256, (NRT == 8 ? 2 : 3)) void tree_gemm(
    const u16* __restrict__ A, const u16* __restrict__ Wm,
    const float* __restrict__ consts,   // leafC[5][1024] or xw[4][4][1024]
    const int* __restrict__ ops,        // nullptr for leaf
    const float* __restrict__ c_in,     // c_init[2][1024] or child c
    float* __restrict__ c_out, u16* __restrict__ h_out,
    int nrows, int m_parents, int is_leaf, float* __restrict__ out_root) {
  constexpr int ROWS = NRT * 16;
  constexpr int COLS = NCT * 16;
  constexpr int S = 64 / NCT;               // stripes (power of 2)
  constexpr int LOG2S = (NCT == 2 ? 5 : 4);
  constexpr int NST = NRT / 2;              // stage loads per thread per chunk
  constexpr int DBUF = NRT * 2048;          // one A buffer, bytes
  constexpr int PASSES = (NRT == 8 ? 2 : 1);
  constexpr int RPP = ROWS / PASSES;        // rows per epilogue pass
  constexpr int FPP = RPP / 16;             // row-frags per pass
  constexpr int SMEM_U16 =
      (4 * RPP * 68 > NRT * 2048 ? 4 * RPP * 68 : NRT * 2048);
  __shared__ __align__(16) u16 smem[SMEM_U16];
  char* smem_c = (char*)smem;

  const int tid = threadIdx.x;
  const int wave = tid >> 6;
  const int lane = tid & 63;
  const int stripe = blockIdx.x & (S - 1);
  const int rowblk = blockIdx.x >> LOG2S;
  const int r0 = rowblk * ROWS;
  const int j0 = stripe * COLS;
  const int ln15 = lane & 15, quad = lane >> 4;
  const int sub = lane >> 3, gsel = lane & 7;

  // ---- A staging sources (XOR-granule swizzle, see r3/r4 — verified) ------
  const char* pAsrc[NST];
  unsigned a_dst[NST];
#pragma unroll
  for (int i = 0; i < NST; ++i) {
    int slot = (wave * NST + i) * 8 + sub;
    int row = r0 + slot; if (row >= nrows) row = nrows - 1;
    pAsrc[i] = (const char*)(A + (size_t)row * 1024 + (unsigned)((gsel ^ sub) * 8));
    a_dst[i] = (unsigned)((wave * NST + i) * 1024 + lane * 16);
  }
  // ---- B direct-load pointers ---------------------------------------------
  const char* pB[NCT];
#pragma unroll
  for (int f = 0; f < NCT; ++f)
    pB[f] = (const char*)(Wm + (size_t)(wave * 1024 + j0 + f * 16 + ln15) * 1024 + quad * 8);

  // ---- A LDS fragment read base (t-offset is the immediate t*2048) --------
  // a_addr(t, ks) = t*2048 + ln15*128 + (((ks*4+quad) ^ (ln15&7)) * 16)
  unsigned a_base[2];
#pragma unroll
  for (int ks = 0; ks < 2; ++ks)
    a_base[ks] = (unsigned)(ln15 * 128 + (((ks * 4 + quad) ^ (ln15 & 7)) * 16));

  f32x4 acc[NRT][NCT];
#pragma unroll
  for (int t = 0; t < NRT; ++t)
#pragma unroll
    for (int f = 0; f < NCT; ++f) acc[t][f] = (f32x4){0.f, 0.f, 0.f, 0.f};

  // prologue: stage chunk 0; load B chunk 0 (both ks) into regs
#pragma unroll
  for (int i = 0; i < NST; ++i)
    __builtin_amdgcn_global_load_lds(
        (const __attribute__((address_space(1))) void*)(pAsrc[i]),
        (__attribute__((address_space(3))) void*)(smem_c + a_dst[i]), 16, 0, 0);
  bf16x8 bcur[2][NCT], bnxt[2][NCT];
#pragma unroll
  for (int ks = 0; ks < 2; ++ks)
#pragma unroll
    for (int f = 0; f < NCT; ++f)
      bcur[ks][f] = *(const bf16x8*)(pB[f] + ks * 64);

#pragma unroll
  for (int ch = 0; ch < 16; ++ch) {
    __syncthreads();  // drains stage(ch) (~1 chunk old) + B(ch) (~3/4 chunk old)
    if (ch < 15) {
#pragma unroll
      for (int i = 0; i < NST; ++i)
        __builtin_amdgcn_global_load_lds(
            (const __attribute__((address_space(1))) void*)(pAsrc[i] + (ch + 1) * 128),
            (__attribute__((address_space(3))) void*)(smem_c + ((ch + 1) & 1) * DBUF + a_dst[i]),
            16, 0, 0);
    }
    const unsigned cb = (unsigned)((ch & 1) * DBUF);
    // ks = 0 : uses only registers + LDS (no vmem wait)
    {
      bf16x8 af[NRT];
#pragma unroll
      for (int t = 0; t < NRT; ++t)
        af[t] = *(const bf16x8*)(smem_c + cb + a_base[0] + t * 2048);
#pragma unroll
      for (int t = 0; t < NRT; ++t)
#pragma unroll
        for (int f = 0; f < NCT; ++f)
          acc[t][f] = __builtin_amdgcn_mfma_f32_16x16x32_bf16(af[t], bcur[0][f],
                                                              acc[t][f], 0, 0, 0);
    }
    // prefetch B for chunk ch+1 (lands well before next barrier's drain)
    if (ch < 15) {
#pragma unroll
      for (int ks = 0; ks < 2; ++ks)
#pragma unroll
        for (int f = 0; f < NCT; ++f)
          bnxt[ks][f] = *(const bf16x8*)(pB[f] + (ch + 1) * 128 + ks * 64);
    }
    // ks = 1
    {
      bf16x8 af[NRT];
#pragma unroll
      for (int t = 0; t < NRT; ++t)
        af[t] = *(const bf16x8*)(smem_c + cb + a_base[1] + t * 2048);
#pragma unroll
      for (int t = 0; t < NRT; ++t)
#pragma unroll
        for (int f = 0; f < NCT; ++f)
          acc[t][f] = __builtin_amdgcn_mfma_f32_16x16x32_bf16(af[t], bcur[1][f],
                                                              acc[t][f], 0, 0, 0);
    }
#pragma unroll
    for (int ks = 0; ks < 2; ++ks)
#pragma unroll
      for (int f = 0; f < NCT; ++f) bcur[ks][f] = bnxt[ks][f];
  }

  // ---- epilogue: PASSES x (RPP rows) through LDS, stride 68 ---------------
#pragma unroll
  for (int pass = 0; pass < PASSES; ++pass) {
    __syncthreads();
#pragma unroll
    for (int tt = 0; tt < FPP; ++tt) {
      int t = pass * FPP + tt;
#pragma unroll
      for (int f = 0; f < NCT; ++f)
#pragma unroll
        for (int k = 0; k < 4; ++k) {
          int row = tt * 16 + quad * 4 + k;
          int col = f * 16 + ln15;
          smem[(wave * RPP + row) * 68 + col] = f2bf(acc[t][f][k]);
        }
    }
    __syncthreads();
    const int rbase = r0 + pass * RPP;

    if (is_leaf) {
      for (int e = tid; e < RPP * COLS; e += 256) {
        int r = e / COLS, j = e % COLS;
        int col = j0 + j, n = rbase + r;
        float p0 = b2f(smem[(0 * RPP + r) * 68 + j]);
        float p1 = b2f(smem[(1 * RPP + r) * 68 + j]);
        float p2 = b2f(smem[(2 * RPP + r) * 68 + j]);
        float p3 = b2f(smem[(3 * RPP + r) * 68 + j]);
        float i_ = sigm(p0 + consts[col]);
        float o_ = sigm(p1 + consts[1024 + col]);
        float u_ = tanhf_(p2 + consts[2048 + col]);
        float f0 = sigm(p3 + consts[3072 + col]);
        float f1 = sigm(p3 + consts[4096 + col]);
        float c = i_ * u_ + f0 * c_in[col] + f1 * c_in[1024 + col];
        float h = o_ * tanhf_(c);
        c_out[(size_t)n * 1024 + col] = c;
        h_out[(size_t)n * 1024 + col] = f2bf(h);
      }
    } else {
      for (int e = tid; e < (RPP / 2) * COLS; e += 256) {
        int p = e / COLS, j = e % COLS;
        int np = (rbase >> 1) + p;
        if (np >= m_parents) break;
        int col = j0 + j;
        int op = ops[np];
        const float* xwop = consts + ((unsigned)(op * 4) << 10);
        float p0a = b2f(smem[(0 * RPP + 2 * p) * 68 + j]), p0b = b2f(smem[(0 * RPP + 2 * p + 1) * 68 + j]);
        float p1a = b2f(smem[(1 * RPP + 2 * p) * 68 + j]), p1b = b2f(smem[(1 * RPP + 2 * p + 1) * 68 + j]);
        float p2a = b2f(smem[(2 * RPP + 2 * p) * 68 + j]), p2b = b2f(smem[(2 * RPP + 2 * p + 1) * 68 + j]);
        float p3a = b2f(smem[(3 * RPP + 2 * p) * 68 + j]), p3b = b2f(smem[(3 * RPP + 2 * p + 1) * 68 + j]);
        float i_ = sigm(p0a + p0b + xwop[col]);
        float o_ = sigm(p1a + p1b + xwop[1024 + col]);
        float u_ = tanhf_(p2a + p2b + xwop[2048 + col]);
        float f0 = sigm(p3a + xwop[3072 + col]);
        float f1 = sigm(p3b + xwop[3072 + col]);
        float c = i_ * u_ + f0 * c_in[(size_t)(rbase + 2 * p) * 1024 + col]
                          + f1 * c_in[(size_t)(rbase + 2 * p + 1) * 1024 + col];
        float h = o_ * tanhf_(c);
        if (m_parents == 1) {
          out_root[col] = c;
          out_root[1024 + col] = h;
        } else {
          c_out[(size_t)np * 1024 + col] = c;
          h_out[(size_t)np * 1024 + col] = f2bf(h);
        }
      }
    }
  }
}

// ---------------------------------------------------------------------------
extern "C" void kernel_launch(void* const* d_in, const int* in_sizes, int n_in,
                              void* d_out, int out_size, void* d_ws, size_t ws_size,
                              hipStream_t stream) {
  const float* tokens = (const float*)d_in[0];
  const int* leaf_ids = (const int*)d_in[1];
  const int* op_ids = (const int*)d_in[2];
  const float* W0 = (const float*)d_in[3];
  const float* W1 = (const float*)d_in[4];
  const float* W2 = (const float*)d_in[5];
  const float* W3 = (const float*)d_in[6];
  const float* U0 = (const float*)d_in[7];
  const float* U1 = (const float*)d_in[8];
  const float* U2 = (const float*)d_in[9];
  const float* U3 = (const float*)d_in[10];
  const float* B0 = (const float*)d_in[11];
  const float* B1 = (const float*)d_in[12];
  const float* B2 = (const float*)d_in[13];
  const float* B3 = (const float*)d_in[14];
  const float* op_emb = (const float*)d_in[15];
  const float* c_init = (const float*)d_in[16];
  const float* h_init = (const float*)d_in[17];
  float* out = (float*)d_out;

  char* ws = (char*)d_ws;
  u16* Wb = (u16*)ws;
  u16* Ub = Wb + (size_t)4 * 1024 * 1024;
  u16* Xl = Ub + (size_t)4 * 1024 * 1024;
  u16* hA = Xl + (size_t)8192 * 1024;
  u16* hB = hA + (size_t)8192 * 1024;
  float* cA = (float*)(hB + (size_t)4096 * 1024);
  float* cB = cA + (size_t)8192 * 1024;
  float* xw = cB + (size_t)4096 * 1024;
  float* lc = xw + 16 * 1024;

  convert_wu_kernel<<<8192, 256, 0, stream>>>(W0, W1, W2, W3, U0, U1, U2, U3, Wb, Ub);
  gather_leaf_kernel<<<8192, 256, 0, stream>>>(tokens, leaf_ids, Xl);
  precompute_kernel<<<84, 256, 0, stream>>>(op_emb, W0, W1, W2, W3, U0, U1, U2, U3,
                                            B0, B1, B2, B3, h_init, xw, lc);

  // leaves: 8192 rows -> <8,2>: 64 rowgroups x 32 stripes
  tree_gemm<8, 2><<<64 * 32, 256, 0, stream>>>(Xl, Wb, lc, nullptr, c_init,
                                               cA, hA, 8192, 0, 1, out);

  const u16* hin = hA; const float* cin = cA;
  u16* hout = hB; float* cout = cB;
  for (int l = 12; l >= 0; --l) {
    int m = 1 << l;
    int nrows = 2 * m;
    if (nrows >= 2048) {
      tree_gemm<8, 2><<<(nrows / 128) * 32, 256, 0, stream>>>(
          hin, Ub, xw, op_ids + (m - 1), cin, cout, hout, nrows, m, 0, out);
    } else if (nrows >= 1024) {
      tree_gemm<4, 2><<<(nrows / 64) * 32, 256, 0, stream>>>(
          hin, Ub, xw, op_ids + (m - 1), cin, cout, hout, nrows, m, 0, out);
    } else {
      int rg = nrows / 32; if (rg < 1) rg = 1;
      tree_gemm<2, 2><<<rg * 32, 256, 0, stream>>>(
          hin, Ub, xw, op_ids + (m - 1), cin, cout, hout, nrows, m, 0, out);
    }
    const u16* th = hin; hin = hout; hout = (u16*)th;
    const float* tc = cin; cin = cout; cout = (float*)tc;
  }
}